// Round 4
// baseline (5119.678 us; speedup 1.0000x reference)
//
#include <hip/hip_runtime.h>
#include <cstddef>
#include <cstdint>

using f32x4  = __attribute__((ext_vector_type(4))) float;
using bf16x8 = __attribute__((ext_vector_type(8))) short;
typedef unsigned short u16;

#define LMDA 0.005f

__device__ __forceinline__ u16 f2bf(float f) {
    union { float f; uint32_t u; } v; v.f = f;
    return (u16)((v.u + 0x7FFFu + ((v.u >> 16) & 1u)) >> 16);
}
__device__ __forceinline__ float bf2f(u16 b) {
    union { uint32_t u; float f; } v; v.u = ((uint32_t)b) << 16;
    return v.f;
}
__device__ __forceinline__ void split2(float x, u16& h, u16& l) {
    h = f2bf(x); l = f2bf(x - bf2f(h));
}
__device__ __forceinline__ float sthr(float x) {
    float ax = fabsf(x) - LMDA;
    return ax > 0.0f ? copysignf(ax, x) : 0.0f;
}

// async 16B global -> LDS (HW writes lane l at ldsbase + l*16)
__device__ __forceinline__ void gload16(const u16* g, u16* l) {
    __builtin_amdgcn_global_load_lds(
        (const __attribute__((address_space(1))) unsigned int*)(const void*)g,
        (__attribute__((address_space(3))) unsigned int*)(void*)l, 16, 0, 0);
}

// ---------------------------------------------------------------------------
// Fused-3 split-bf16 NT GEMM + fused ISTA epilogue. Fixed K=1024, ld=1024.
//   acc[m][n] = sum_k Ah*Bh + Al*Bh + Ah*Bl
// Tile 128x64, 8 waves = 2(mr) x 2(nc) x 2(ks: splits the two K=32 halves of
// each BK=64 slab). Wavetile 64x32 = 4x2 frags of mfma_f32_16x16x32_bf16.
// LDS: 2 x 48KB buffers of fragment-ordered 1KB chunks (lane*16B: matches
// global_load_lds' linear dest AND gives conflict-free ds_read_b128).
// 2-phase pipeline: stage(next) issued before compute(cur); vmcnt(0)+s_barrier
// once per step. End: 2-way ks reduce via LDS, then fused epilogue:
// EPI 0: OutF = acc                      (final out = R@U)
// EPI 1: OutF = 0.2*acc; R = split(st(OutF))    (Csc and R1 together)
// EPI 2: OutH/L = split(I - 0.2*acc)     (W = I - 0.2*U@U^T)
// EPI 3: OutH/L = split(st(acc + Cs))    (ISTA step)
// ---------------------------------------------------------------------------
template<int EPI>
__global__ __launch_bounds__(512)
void gemm_ista(const u16* __restrict__ Ah, const u16* __restrict__ Al,
               const u16* __restrict__ Bh, const u16* __restrict__ Bl,
               int Nt,
               const float* __restrict__ Cs, float* __restrict__ OutF,
               u16* __restrict__ OutH, u16* __restrict__ OutL)
{
    __shared__ __align__(16) u16 S[2][48 * 512];   // 96 KiB

    // XCD-aware bijective swizzle (grids are multiples of 8)
    const int nwg = gridDim.x;
    const int fid = blockIdx.x;
    const int sid = (fid & 7) * (nwg >> 3) + (fid >> 3);
    const int row0 = (sid / Nt) << 7;
    const int col0 = (sid % Nt) << 6;

    const int tid  = threadIdx.x;
    const int lane = tid & 63;
    const int w    = tid >> 6;      // 0..7
    const int mr = w >> 2, nc = (w >> 1) & 1, ks = w & 1;

    // ---- staging roles: 48 chunks of 1KB, 6 per wave ----
    // A chunks [0,32): idx = (h<<4)+(kss<<3)+mi  (mi = 16-row group 0..7)
    // B chunks [32,48): 32 + (h<<3)+(kss<<2)+ni  (ni 0..3)
    // chunk source: lane l <- M[r0 + g*16 + (l&15)][koff + kss*32 + (l>>4)*8 ..+8)
    const u16* gb[6];
    int cf[6];
    #pragma unroll
    for (int t = 0; t < 6; ++t) {
        const int c = w * 6 + t;
        const u16* base; int r;
        int kss;
        if (c < 32) {
            const int h = (c >> 4) & 1; kss = (c >> 3) & 1;
            base = h ? Al : Ah;
            r = row0 + ((c & 7) << 4) + (lane & 15);
        } else {
            const int cb = c - 32;
            const int h = (cb >> 3) & 1; kss = (cb >> 2) & 1;
            base = h ? Bl : Bh;
            r = col0 + ((cb & 3) << 4) + (lane & 15);
        }
        gb[t] = base + ((size_t)r << 10) + (kss << 5) + ((lane >> 4) << 3);
        cf[t] = c << 9;
    }
    auto stage = [&](int b, int koff) {
        #pragma unroll
        for (int t = 0; t < 6; ++t)
            gload16(gb[t] + koff, &S[b][cf[t]]);
    };

    f32x4 acc[4][2] = {};

    stage(0, 0);
    asm volatile("s_waitcnt vmcnt(0)" ::: "memory");
    __builtin_amdgcn_s_barrier();
    asm volatile("" ::: "memory");

    int cur = 0;
    for (int s = 0; s < 16; ++s) {
        if (s < 15) stage(cur ^ 1, (s + 1) << 6);

        const u16* Sb = S[cur];
        const int ab = (ks << 3) + (mr << 2);              // A(h=0, ks, mr*4+i)
        const int bb = 32 + (ks << 2) + (nc << 1);         // B(h=0, ks, nc*2+j)
        bf16x8 ah[4], al[4], bh[2], bl[2];
        #pragma unroll
        for (int i = 0; i < 4; ++i) {
            ah[i] = *(const bf16x8*)&Sb[(ab + i)      * 512 + (lane << 3)];
            al[i] = *(const bf16x8*)&Sb[(ab + 16 + i) * 512 + (lane << 3)];
        }
        #pragma unroll
        for (int j = 0; j < 2; ++j) {
            bh[j] = *(const bf16x8*)&Sb[(bb + j)     * 512 + (lane << 3)];
            bl[j] = *(const bf16x8*)&Sb[(bb + 8 + j) * 512 + (lane << 3)];
        }
        #pragma unroll
        for (int i = 0; i < 4; ++i)
            #pragma unroll
            for (int j = 0; j < 2; ++j)
                acc[i][j] = __builtin_amdgcn_mfma_f32_16x16x32_bf16(ah[i], bh[j], acc[i][j], 0, 0, 0);
        #pragma unroll
        for (int i = 0; i < 4; ++i)
            #pragma unroll
            for (int j = 0; j < 2; ++j)
                acc[i][j] = __builtin_amdgcn_mfma_f32_16x16x32_bf16(al[i], bh[j], acc[i][j], 0, 0, 0);
        #pragma unroll
        for (int i = 0; i < 4; ++i)
            #pragma unroll
            for (int j = 0; j < 2; ++j)
                acc[i][j] = __builtin_amdgcn_mfma_f32_16x16x32_bf16(ah[i], bl[j], acc[i][j], 0, 0, 0);

        asm volatile("s_waitcnt vmcnt(0)" ::: "memory");
        __builtin_amdgcn_s_barrier();
        asm volatile("" ::: "memory");
        cur ^= 1;
    }

    // ---- 2-way ks reduce via LDS (32KB region of S[0], now dead) ----
    float* red = (float*)&S[0][0];
    const int at = (((mr << 1) + nc) << 6) + lane;   // 0..255
    if (ks == 1) {
        #pragma unroll
        for (int p = 0; p < 8; ++p)
            *(f32x4*)&red[(((p << 8) + at) << 2)] = acc[p >> 1][p & 1];
    }
    __syncthreads();
    if (ks == 0) {
        #pragma unroll
        for (int p = 0; p < 8; ++p)
            acc[p >> 1][p & 1] += *(const f32x4*)&red[(((p << 8) + at) << 2)];

        // C/D layout: col = lane&15, row = (lane>>4)*4 + e  (m89/m91 verified)
        const int gr0 = row0 + (mr << 6) + ((lane >> 4) << 2);
        const int gc  = col0 + (nc << 5) + (lane & 15);
        #pragma unroll
        for (int i = 0; i < 4; ++i) {
            #pragma unroll
            for (int j = 0; j < 2; ++j) {
                #pragma unroll
                for (int e = 0; e < 4; ++e) {
                    const int grow = gr0 + (i << 4) + e;
                    const int gcol = gc + (j << 4);
                    const size_t idx = ((size_t)grow << 10) + gcol;
                    const float p = acc[i][j][e];
                    if (EPI == 0) {
                        OutF[idx] = p;
                    } else if (EPI == 1) {
                        float f = 0.2f * p;
                        OutF[idx] = f;
                        u16 h, l; split2(sthr(f), h, l);
                        OutH[idx] = h; OutL[idx] = l;
                    } else if (EPI == 2) {
                        float x = (grow == gcol ? 1.0f : 0.0f) - 0.2f * p;
                        u16 h, l; split2(x, h, l);
                        OutH[idx] = h; OutL[idx] = l;
                    } else {
                        float x = p + Cs[idx];
                        u16 h, l; split2(sthr(x), h, l);
                        OutH[idx] = h; OutL[idx] = l;
                    }
                }
            }
        }
    }
}

// fp32 -> (hi, lo) bf16 pair, elementwise
__global__ void k_split(const float* __restrict__ in, u16* __restrict__ hi,
                        u16* __restrict__ lo, int n)
{
    int i = blockIdx.x * 256 + threadIdx.x;
    if (i < n) { u16 h, l; split2(in[i], h, l); hi[i] = h; lo[i] = l; }
}

// Ut[j][k] = U[k][j] as bf16 pair (32x32 LDS tile, padded)
__global__ __launch_bounds__(256)
void k_transpose_split(const float* __restrict__ in, u16* __restrict__ hi,
                       u16* __restrict__ lo)
{
    __shared__ float t[32][33];
    const int bx = blockIdx.x, by = blockIdx.y;
    const int lx = threadIdx.x & 31, ly = threadIdx.x >> 5;
    #pragma unroll
    for (int rr = 0; rr < 4; ++rr) {
        int r = ly * 4 + rr;
        t[r][lx] = in[(size_t)(by * 32 + r) * 1024 + bx * 32 + lx];
    }
    __syncthreads();
    #pragma unroll
    for (int rr = 0; rr < 4; ++rr) {
        int r = ly * 4 + rr;
        u16 h, l; split2(t[lx][r], h, l);
        size_t idx = (size_t)(bx * 32 + r) * 1024 + by * 32 + lx;
        hi[idx] = h; lo[idx] = l;
    }
}

extern "C" void kernel_launch(void* const* d_in, const int* in_sizes, int n_in,
                              void* d_out, int out_size, void* d_ws, size_t ws_size,
                              hipStream_t stream) {
    const float* img = (const float*)d_in[0];   // (2048, 1024) fp32
    const float* U   = (const float*)d_in[1];   // (1024, 1024) fp32
    float* out = (float*)d_out;                 // (2048, 1024) fp32

    char* ws = (char*)d_ws;
    auto MB = [](size_t m) { return m << 20; };
    u16*   Uh  = (u16*)(ws + MB(0));
    u16*   Ul  = (u16*)(ws + MB(2));
    u16*   Uth = (u16*)(ws + MB(4));
    u16*   Utl = (u16*)(ws + MB(6));
    u16*   Wh  = (u16*)(ws + MB(8));
    u16*   Wl  = (u16*)(ws + MB(10));
    float* Csc = (float*)(ws + MB(12));          // 8 MB
    u16*   Rah = (u16*)(ws + MB(20));
    u16*   Ral = (u16*)(ws + MB(24));
    u16*   Rbh = (u16*)(ws + MB(28));
    u16*   Rbl = (u16*)(ws + MB(32));            // ends at 36 MB
    u16*   Ih  = Rbh;   // img split lives only until Csc is built
    u16*   Il  = Rbl;

    // ---- prologue ----
    k_split<<<4096, 256, 0, stream>>>(U, Uh, Ul, 1024 * 1024);
    k_split<<<8192, 256, 0, stream>>>(img, Ih, Il, 2048 * 1024);
    k_transpose_split<<<dim3(32, 32), 256, 0, stream>>>(U, Uth, Utl);

    // W = I - 0.2 * U @ U^T   (M=1024 -> 8x16 = 128 blocks)
    gemm_ista<2><<<128, 512, 0, stream>>>(Uh, Ul, Uh, Ul, 16,
                                          nullptr, nullptr, Wh, Wl);

    // Csc = 0.2 * img @ U^T ; R1 = st(Csc)   (16x16 = 256 blocks)
    gemm_ista<1><<<256, 512, 0, stream>>>(Ih, Il, Uh, Ul, 16,
                                          nullptr, Csc, Rah, Ral);

    // ---- iterations 2..150: R <- st(R @ W + Csc) ----
    u16 *ch = Rah, *cl = Ral, *nh = Rbh, *nl = Rbl;
    for (int it = 0; it < 149; ++it) {
        gemm_ista<3><<<256, 512, 0, stream>>>(ch, cl, Wh, Wl, 16,
                                              Csc, nullptr, nh, nl);
        u16* t;
        t = ch; ch = nh; nh = t;
        t = cl; cl = nl; nl = t;
    }

    // ---- out = R @ U (NT against U^T) ----
    gemm_ista<0><<<256, 512, 0, stream>>>(ch, cl, Uth, Utl, 16,
                                          nullptr, out, nullptr, nullptr);
}

// Round 5
// 5046.174 us; speedup vs baseline: 1.0146x; 1.0146x over previous
//
#include <hip/hip_runtime.h>
#include <cstddef>
#include <cstdint>

using f32x4  = __attribute__((ext_vector_type(4))) float;
using bf16x8 = __attribute__((ext_vector_type(8))) short;
typedef unsigned short u16;

#define LMDA 0.005f

__device__ __forceinline__ u16 f2bf(float f) {
    union { float f; uint32_t u; } v; v.f = f;
    return (u16)((v.u + 0x7FFFu + ((v.u >> 16) & 1u)) >> 16);
}
__device__ __forceinline__ float bf2f(u16 b) {
    union { uint32_t u; float f; } v; v.u = ((uint32_t)b) << 16;
    return v.f;
}
__device__ __forceinline__ void split2(float x, u16& h, u16& l) {
    h = f2bf(x); l = f2bf(x - bf2f(h));
}
__device__ __forceinline__ float sthr(float x) {
    float ax = fabsf(x) - LMDA;
    return ax > 0.0f ? copysignf(ax, x) : 0.0f;
}

// async 16B global -> LDS (HW writes lane l at ldsbase + l*16)
__device__ __forceinline__ void gload16(const u16* g, u16* l) {
    __builtin_amdgcn_global_load_lds(
        (const __attribute__((address_space(1))) unsigned int*)(const void*)g,
        (__attribute__((address_space(3))) unsigned int*)(void*)l, 16, 0, 0);
}

// ---------------------------------------------------------------------------
// Fused-3 split-bf16 NT GEMM + fused ISTA epilogue. Fixed K=1024, ld=1024.
//   acc[m][n] = sum_k Ah*Bh + Al*Bh + Ah*Bl
// Tile 128x64, 8 waves = 2(mr) x 2(nc) x 2(ks). Wavetile 64x32 = 4x2 frags of
// mfma_f32_16x16x32_bf16. 16 k-steps of BK=64.
// LDS: 3 x 48KB fragment-ordered buffers (lane*16B: matches global_load_lds
// linear dest AND conflict-free ds_read_b128).
// Pipeline (T4, counted vmcnt — never 0 in loop): per step
//   vmcnt(6) [own stage(s) done; stage(s+1) stays in flight] -> s_barrier ->
//   issue stage(s+2) -> ds_read buf[s] + 24 MFMA.
// stage(s+2) overwrites buf[(s-1)%3]; it is issued only after the step-s
// barrier, which all waves reach only after finishing step-(s-1) reads: safe
// with ONE barrier per step.
// Epilogue: 2-way ks reduce via LDS, work split across both ks halves.
// EPI 0: OutF = acc                      (final out = R@U)
// EPI 1: OutF = 0.2*acc; R = split(st(OutF))    (Csc and R1 together)
// EPI 2: OutH/L = split(I - 0.2*acc)     (W = I - 0.2*U@U^T)
// EPI 3: OutH/L = split(st(acc + Cs))    (ISTA step)
// ---------------------------------------------------------------------------
template<int EPI>
__global__ __launch_bounds__(512, 2)
void gemm_ista(const u16* __restrict__ Ah, const u16* __restrict__ Al,
               const u16* __restrict__ Bh, const u16* __restrict__ Bl,
               int Nt,
               const float* __restrict__ Cs, float* __restrict__ OutF,
               u16* __restrict__ OutH, u16* __restrict__ OutL)
{
    __shared__ __align__(16) u16 S[3][48 * 512];   // 144 KiB

    // XCD-aware bijective swizzle (grids are multiples of 8)
    const int nwg = gridDim.x;
    const int fid = blockIdx.x;
    const int sid = (fid & 7) * (nwg >> 3) + (fid >> 3);
    const int row0 = (sid / Nt) << 7;
    const int col0 = (sid % Nt) << 6;

    const int tid  = threadIdx.x;
    const int lane = tid & 63;
    const int w    = tid >> 6;      // 0..7
    const int mr = w >> 2, nc = (w >> 1) & 1, ks = w & 1;

    // ---- staging roles: 48 chunks of 1KB, 6 per wave ----
    // A chunks [0,32): idx = (h<<4)+(kss<<3)+mi ; B chunks [32,48): 32+(h<<3)+(kss<<2)+ni
    // chunk source: lane l <- M[r0 + g*16 + (l&15)][koff + kss*32 + (l>>4)*8 ..+8)
    const u16* gb[6];
    int cf[6];
    #pragma unroll
    for (int t = 0; t < 6; ++t) {
        const int c = w * 6 + t;
        const u16* base; int r; int kss;
        if (c < 32) {
            const int h = (c >> 4) & 1; kss = (c >> 3) & 1;
            base = h ? Al : Ah;
            r = row0 + ((c & 7) << 4) + (lane & 15);
        } else {
            const int cb = c - 32;
            const int h = (cb >> 3) & 1; kss = (cb >> 2) & 1;
            base = h ? Bl : Bh;
            r = col0 + ((cb & 3) << 4) + (lane & 15);
        }
        gb[t] = base + ((size_t)r << 10) + (kss << 5) + ((lane >> 4) << 3);
        cf[t] = c << 9;
    }
    auto stage = [&](int b, int koff) {
        #pragma unroll
        for (int t = 0; t < 6; ++t)
            gload16(gb[t] + koff, &S[b][cf[t]]);
    };

    f32x4 acc[4][2] = {};

    stage(0, 0);
    stage(1, 64);

    #pragma unroll
    for (int s = 0; s < 16; ++s) {
        if (s <= 14) asm volatile("s_waitcnt vmcnt(6)" ::: "memory");
        else         asm volatile("s_waitcnt vmcnt(0)" ::: "memory");
        __builtin_amdgcn_s_barrier();
        asm volatile("" ::: "memory");
        if (s + 2 < 16) stage((s + 2) % 3, (s + 2) << 6);

        const u16* Sb = S[s % 3];
        const int ab = (ks << 3) + (mr << 2);              // A(h=0, ks, mr*4+i)
        const int bb = 32 + (ks << 2) + (nc << 1);         // B(h=0, ks, nc*2+j)
        bf16x8 ah[4], al[4], bh[2], bl[2];
        #pragma unroll
        for (int i = 0; i < 4; ++i) {
            ah[i] = *(const bf16x8*)&Sb[(ab + i)      * 512 + (lane << 3)];
            al[i] = *(const bf16x8*)&Sb[(ab + 16 + i) * 512 + (lane << 3)];
        }
        #pragma unroll
        for (int j = 0; j < 2; ++j) {
            bh[j] = *(const bf16x8*)&Sb[(bb + j)     * 512 + (lane << 3)];
            bl[j] = *(const bf16x8*)&Sb[(bb + 8 + j) * 512 + (lane << 3)];
        }
        #pragma unroll
        for (int i = 0; i < 4; ++i)
            #pragma unroll
            for (int j = 0; j < 2; ++j)
                acc[i][j] = __builtin_amdgcn_mfma_f32_16x16x32_bf16(ah[i], bh[j], acc[i][j], 0, 0, 0);
        #pragma unroll
        for (int i = 0; i < 4; ++i)
            #pragma unroll
            for (int j = 0; j < 2; ++j)
                acc[i][j] = __builtin_amdgcn_mfma_f32_16x16x32_bf16(al[i], bh[j], acc[i][j], 0, 0, 0);
        #pragma unroll
        for (int i = 0; i < 4; ++i)
            #pragma unroll
            for (int j = 0; j < 2; ++j)
                acc[i][j] = __builtin_amdgcn_mfma_f32_16x16x32_bf16(ah[i], bl[j], acc[i][j], 0, 0, 0);
        asm volatile("" ::: "memory");
    }

    // ---- 2-way ks reduce via LDS; epilogue split across both ks halves ----
    // giver: ks0 contributes i in {2,3}; ks1 contributes i in {0,1}.
    // consumer: ks0 finishes i in {0,1}; ks1 finishes i in {2,3}.
    __syncthreads();
    f32x4* red = (f32x4*)&S[0][0];   // 32 slots x 64 lanes x 16B = 32KB
    const int wquad = (mr << 1) + nc;
    #pragma unroll
    for (int ih = 0; ih < 2; ++ih) {
        #pragma unroll
        for (int j = 0; j < 2; ++j) {
            const int isrc = ks ? ih : (2 + ih);
            const int slot = ((((wquad << 1) | ks) << 2) | (ih << 1) | j);
            red[slot * 64 + lane] = acc[isrc][j];
        }
    }
    __syncthreads();

    // C/D layout: col = lane&15, row = (lane>>4)*4 + e  (m89/m91 verified)
    const int gr0 = row0 + (mr << 6) + ((lane >> 4) << 2);
    const int gc  = col0 + (nc << 5) + (lane & 15);
    #pragma unroll
    for (int ih = 0; ih < 2; ++ih) {
        #pragma unroll
        for (int j = 0; j < 2; ++j) {
            const int i    = ks ? (2 + ih) : ih;
            const int slot = ((((wquad << 1) | (ks ^ 1)) << 2) | (ih << 1) | j);
            f32x4 sum = acc[i][j] + red[slot * 64 + lane];
            #pragma unroll
            for (int e = 0; e < 4; ++e) {
                const int grow = gr0 + (i << 4) + e;
                const int gcol = gc + (j << 4);
                const size_t idx = ((size_t)grow << 10) + gcol;
                const float p = sum[e];
                if (EPI == 0) {
                    OutF[idx] = p;
                } else if (EPI == 1) {
                    float f = 0.2f * p;
                    OutF[idx] = f;
                    u16 h, l; split2(sthr(f), h, l);
                    OutH[idx] = h; OutL[idx] = l;
                } else if (EPI == 2) {
                    float x = (grow == gcol ? 1.0f : 0.0f) - 0.2f * p;
                    u16 h, l; split2(x, h, l);
                    OutH[idx] = h; OutL[idx] = l;
                } else {
                    float x = p + Cs[idx];
                    u16 h, l; split2(sthr(x), h, l);
                    OutH[idx] = h; OutL[idx] = l;
                }
            }
        }
    }
}

// fp32 -> (hi, lo) bf16 pair, elementwise
__global__ void k_split(const float* __restrict__ in, u16* __restrict__ hi,
                        u16* __restrict__ lo, int n)
{
    int i = blockIdx.x * 256 + threadIdx.x;
    if (i < n) { u16 h, l; split2(in[i], h, l); hi[i] = h; lo[i] = l; }
}

// Ut[j][k] = U[k][j] as bf16 pair (32x32 LDS tile, padded)
__global__ __launch_bounds__(256)
void k_transpose_split(const float* __restrict__ in, u16* __restrict__ hi,
                       u16* __restrict__ lo)
{
    __shared__ float t[32][33];
    const int bx = blockIdx.x, by = blockIdx.y;
    const int lx = threadIdx.x & 31, ly = threadIdx.x >> 5;
    #pragma unroll
    for (int rr = 0; rr < 4; ++rr) {
        int r = ly * 4 + rr;
        t[r][lx] = in[(size_t)(by * 32 + r) * 1024 + bx * 32 + lx];
    }
    __syncthreads();
    #pragma unroll
    for (int rr = 0; rr < 4; ++rr) {
        int r = ly * 4 + rr;
        u16 h, l; split2(t[lx][r], h, l);
        size_t idx = (size_t)(bx * 32 + r) * 1024 + by * 32 + lx;
        hi[idx] = h; lo[idx] = l;
    }
}

extern "C" void kernel_launch(void* const* d_in, const int* in_sizes, int n_in,
                              void* d_out, int out_size, void* d_ws, size_t ws_size,
                              hipStream_t stream) {
    const float* img = (const float*)d_in[0];   // (2048, 1024) fp32
    const float* U   = (const float*)d_in[1];   // (1024, 1024) fp32
    float* out = (float*)d_out;                 // (2048, 1024) fp32

    char* ws = (char*)d_ws;
    auto MB = [](size_t m) { return m << 20; };
    u16*   Uh  = (u16*)(ws + MB(0));
    u16*   Ul  = (u16*)(ws + MB(2));
    u16*   Uth = (u16*)(ws + MB(4));
    u16*   Utl = (u16*)(ws + MB(6));
    u16*   Wh  = (u16*)(ws + MB(8));
    u16*   Wl  = (u16*)(ws + MB(10));
    float* Csc = (float*)(ws + MB(12));          // 8 MB
    u16*   Rah = (u16*)(ws + MB(20));
    u16*   Ral = (u16*)(ws + MB(24));
    u16*   Rbh = (u16*)(ws + MB(28));
    u16*   Rbl = (u16*)(ws + MB(32));            // ends at 36 MB
    u16*   Ih  = Rbh;   // img split lives only until Csc is built
    u16*   Il  = Rbl;

    // ---- prologue ----
    k_split<<<4096, 256, 0, stream>>>(U, Uh, Ul, 1024 * 1024);
    k_split<<<8192, 256, 0, stream>>>(img, Ih, Il, 2048 * 1024);
    k_transpose_split<<<dim3(32, 32), 256, 0, stream>>>(U, Uth, Utl);

    // W = I - 0.2 * U @ U^T   (M=1024 -> 8x16 = 128 blocks)
    gemm_ista<2><<<128, 512, 0, stream>>>(Uh, Ul, Uh, Ul, 16,
                                          nullptr, nullptr, Wh, Wl);

    // Csc = 0.2 * img @ U^T ; R1 = st(Csc)   (16x16 = 256 blocks)
    gemm_ista<1><<<256, 512, 0, stream>>>(Ih, Il, Uh, Ul, 16,
                                          nullptr, Csc, Rah, Ral);

    // ---- iterations 2..150: R <- st(R @ W + Csc) ----
    u16 *ch = Rah, *cl = Ral, *nh = Rbh, *nl = Rbl;
    for (int it = 0; it < 149; ++it) {
        gemm_ista<3><<<256, 512, 0, stream>>>(ch, cl, Wh, Wl, 16,
                                              Csc, nullptr, nh, nl);
        u16* t;
        t = ch; ch = nh; nh = t;
        t = cl; cl = nl; nl = t;
    }

    // ---- out = R @ U (NT against U^T) ----
    gemm_ista<0><<<256, 512, 0, stream>>>(ch, cl, Uth, Utl, 16,
                                          nullptr, out, nullptr, nullptr);
}